// Round 1
// baseline (269.724 us; speedup 1.0000x reference)
//
#include <hip/hip_runtime.h>

#define B_   2
#define LQ   1024
#define LIN  4096
#define CH   256
#define MH   8
#define NP   4

// ---------------------------------------------------------------------------
// C[M,N] = A[M,K] * B[N,K]^T + bias[N]   (both operands K-contiguous, "NT")
// 64x64 block tile, BK=16, 256 threads, 4x4 micro-tile per thread.
// ---------------------------------------------------------------------------
__global__ __launch_bounds__(256)
void gemm_nt_bias(const float* __restrict__ A, const float* __restrict__ B,
                  const float* __restrict__ bias, float* __restrict__ C,
                  int M, int N, int K) {
    __shared__ float As[16][64];
    __shared__ float Bs[16][64];
    const int tid = threadIdx.x;
    const int bm  = blockIdx.x * 64;
    const int bn  = blockIdx.y * 64;
    const int tx  = tid & 15;        // col group
    const int ty  = tid >> 4;        // row group
    const int lm  = tid >> 2;        // staging row within tile
    const int lk  = (tid & 3) << 2;  // staging k offset (0,4,8,12)

    const float* Ap = A + (size_t)(bm + lm) * K + lk;
    const float* Bp = B + (size_t)(bn + lm) * K + lk;

    float acc[4][4] = {};
    for (int k0 = 0; k0 < K; k0 += 16) {
        float4 av = *reinterpret_cast<const float4*>(Ap + k0);
        float4 bv = *reinterpret_cast<const float4*>(Bp + k0);
        __syncthreads();
        As[lk + 0][lm] = av.x; As[lk + 1][lm] = av.y;
        As[lk + 2][lm] = av.z; As[lk + 3][lm] = av.w;
        Bs[lk + 0][lm] = bv.x; Bs[lk + 1][lm] = bv.y;
        Bs[lk + 2][lm] = bv.z; Bs[lk + 3][lm] = bv.w;
        __syncthreads();
#pragma unroll
        for (int k = 0; k < 16; ++k) {
            float4 a = *reinterpret_cast<const float4*>(&As[k][ty << 2]);
            float4 b = *reinterpret_cast<const float4*>(&Bs[k][tx << 2]);
            float ar[4] = {a.x, a.y, a.z, a.w};
            float br[4] = {b.x, b.y, b.z, b.w};
#pragma unroll
            for (int i = 0; i < 4; ++i)
#pragma unroll
                for (int j = 0; j < 4; ++j)
                    acc[i][j] = fmaf(ar[i], br[j], acc[i][j]);
        }
    }
#pragma unroll
    for (int i = 0; i < 4; ++i) {
        const int row = bm + (ty << 2) + i;
        const int col = bn + (tx << 2);
        float4 c;
        c.x = acc[i][0] + bias[col + 0];
        c.y = acc[i][1] + bias[col + 1];
        c.z = acc[i][2] + bias[col + 2];
        c.w = acc[i][3] + bias[col + 3];
        *reinterpret_cast<float4*>(C + (size_t)row * N + col) = c;
    }
}

// ---------------------------------------------------------------------------
// Pack Ws(96x256) and Wa(32x256) (+biases) into one 128x256 weight matrix.
// ---------------------------------------------------------------------------
__global__ void pack_wsa(const float* __restrict__ Ws, const float* __restrict__ bs,
                         const float* __restrict__ Wa, const float* __restrict__ ba,
                         float* __restrict__ Wsa, float* __restrict__ bsa) {
    int j = blockIdx.x, k = threadIdx.x;
    Wsa[j * CH + k] = (j < 96) ? Ws[j * CH + k] : Wa[(j - 96) * CH + k];
    if (k == 0) bsa[j] = (j < 96) ? bs[j] : ba[j - 96];
}

// ---------------------------------------------------------------------------
// From S = query @ [Ws;Wa]^T + [bs;ba]  (2048 x 128):
//   loc[b,q,m,p,:]  = query_points[b,q,:] + S[row][m*12 + p*3 + e]
//   attw[b,q,m,p]   = softmax_p(S[row][96 + m*4 + p])
// one thread per (b,q,m): 16384 threads.
// ---------------------------------------------------------------------------
__global__ __launch_bounds__(256)
void loc_attw_kernel(const float* __restrict__ S, const float* __restrict__ qpts,
                     float* __restrict__ loc, float* __restrict__ attw) {
    int t = blockIdx.x * 256 + threadIdx.x;    // [0, 16384)
    int m = t & 7;
    int r = t >> 3;                            // row in [0, 2048)
    const float* Sr = S + (size_t)r * 128;
    float q0 = qpts[r * 3 + 0], q1 = qpts[r * 3 + 1], q2 = qpts[r * 3 + 2];
#pragma unroll
    for (int p = 0; p < NP; ++p) {
        size_t o = ((size_t)(r * MH + m) * NP + p) * 3;
        loc[o + 0] = q0 + Sr[m * 12 + p * 3 + 0];
        loc[o + 1] = q1 + Sr[m * 12 + p * 3 + 1];
        loc[o + 2] = q2 + Sr[m * 12 + p * 3 + 2];
    }
    float l0 = Sr[96 + m * 4 + 0], l1 = Sr[96 + m * 4 + 1];
    float l2 = Sr[96 + m * 4 + 2], l3 = Sr[96 + m * 4 + 3];
    float mx = fmaxf(fmaxf(l0, l1), fmaxf(l2, l3));
    float e0 = expf(l0 - mx), e1 = expf(l1 - mx);
    float e2 = expf(l2 - mx), e3 = expf(l3 - mx);
    float inv = 1.0f / (e0 + e1 + e2 + e3);
    size_t ao = (size_t)(r * MH + m) * NP;
    attw[ao + 0] = e0 * inv; attw[ao + 1] = e1 * inv;
    attw[ao + 2] = e2 * inv; attw[ao + 3] = e3 * inv;
}

// ---------------------------------------------------------------------------
// Fused distance + argmin (k=1 KNN). One thread per sampling point.
// Candidate points staged in LDS as float4(x,y,z,|v|^2); broadcast reads.
// d = |v|^2 - 2 s.v  (|s|^2 is constant per row -> irrelevant to argmin).
// 4 independent trackers break the min-chain dependency; strict < keeps the
// first index on ties (matches jnp.argmin).
// ---------------------------------------------------------------------------
__global__ __launch_bounds__(128)
void knn_kernel(const float* __restrict__ loc, const float* __restrict__ ipts,
                int* __restrict__ idx) {
    int gq = blockIdx.x * 128 + threadIdx.x;   // [0, 65536)
    int b  = gq >> 15;                          // NQ = 32768 per batch
    float sx = loc[(size_t)gq * 3 + 0];
    float sy = loc[(size_t)gq * 3 + 1];
    float sz = loc[(size_t)gq * 3 + 2];
    float sx2 = -2.f * sx, sy2 = -2.f * sy, sz2 = -2.f * sz;

    __shared__ float4 pts[512];
    const float* pb = ipts + (size_t)b * LIN * 3;

    float bd0 = 1e30f, bd1 = 1e30f, bd2 = 1e30f, bd3 = 1e30f;
    int   bi0 = 0, bi1 = 0, bi2 = 0, bi3 = 0;

    for (int t0 = 0; t0 < LIN; t0 += 512) {
        __syncthreads();
        {
            // each thread stages 4 points = 12 floats (3 aligned float4 loads)
            const float* sp = pb + (size_t)t0 * 3 + threadIdx.x * 12;
            float4 u0 = *reinterpret_cast<const float4*>(sp + 0);
            float4 u1 = *reinterpret_cast<const float4*>(sp + 4);
            float4 u2 = *reinterpret_cast<const float4*>(sp + 8);
            float xs[4] = {u0.x, u0.w, u1.z, u2.y};
            float ys[4] = {u0.y, u1.x, u1.w, u2.z};
            float zs[4] = {u0.z, u1.y, u2.x, u2.w};
#pragma unroll
            for (int i = 0; i < 4; ++i) {
                float nrm = fmaf(zs[i], zs[i], fmaf(ys[i], ys[i], xs[i] * xs[i]));
                pts[threadIdx.x * 4 + i] = make_float4(xs[i], ys[i], zs[i], nrm);
            }
        }
        __syncthreads();
#pragma unroll 2
        for (int l = 0; l < 512; l += 4) {
            float4 p0 = pts[l + 0];
            float4 p1 = pts[l + 1];
            float4 p2 = pts[l + 2];
            float4 p3 = pts[l + 3];
            float d0 = fmaf(sx2, p0.x, fmaf(sy2, p0.y, fmaf(sz2, p0.z, p0.w)));
            float d1 = fmaf(sx2, p1.x, fmaf(sy2, p1.y, fmaf(sz2, p1.z, p1.w)));
            float d2 = fmaf(sx2, p2.x, fmaf(sy2, p2.y, fmaf(sz2, p2.z, p2.w)));
            float d3 = fmaf(sx2, p3.x, fmaf(sy2, p3.y, fmaf(sz2, p3.z, p3.w)));
            if (d0 < bd0) { bd0 = d0; bi0 = t0 + l + 0; }
            if (d1 < bd1) { bd1 = d1; bi1 = t0 + l + 1; }
            if (d2 < bd2) { bd2 = d2; bi2 = t0 + l + 2; }
            if (d3 < bd3) { bd3 = d3; bi3 = t0 + l + 3; }
        }
    }
    // lexicographic (d, i) merge -> global first-minimum, matching argmin ties
    if (bd1 < bd0 || (bd1 == bd0 && bi1 < bi0)) { bd0 = bd1; bi0 = bi1; }
    if (bd2 < bd0 || (bd2 == bd0 && bi2 < bi0)) { bd0 = bd2; bi0 = bi2; }
    if (bd3 < bd0 || (bd3 == bd0 && bi3 < bi0)) { bd0 = bd3; bi0 = bi3; }
    idx[gq] = bi0;
}

// ---------------------------------------------------------------------------
// out1[b,q,c] = sum_p attw[b,q,m,p] * value[b, idx[b,q,m,p], m, d]   (c=m*32+d)
// one block per (b,q), 256 threads = one channel each. Gathers are 128B
// coalesced per (m,p) group (32 consecutive lanes, consecutive d).
// ---------------------------------------------------------------------------
__global__ __launch_bounds__(256)
void gather_kernel(const float* __restrict__ value, const float* __restrict__ attw,
                   const int* __restrict__ idx, float* __restrict__ out1) {
    int bq = blockIdx.x;                 // b*LQ + q
    int c  = threadIdx.x;
    int m  = c >> 5;
    int b  = bq >> 10;
    size_t base = ((size_t)bq * MH + m) * NP;
    const float* vb = value + (size_t)b * LIN * CH;
    float acc = 0.f;
#pragma unroll
    for (int p = 0; p < NP; ++p) {
        int   i = idx[base + p];
        float w = attw[base + p];
        acc = fmaf(w, vb[(size_t)i * CH + c], acc);
    }
    out1[(size_t)bq * CH + c] = acc;
}

// ---------------------------------------------------------------------------
extern "C" void kernel_launch(void* const* d_in, const int* in_sizes, int n_in,
                              void* d_out, int out_size, void* d_ws, size_t ws_size,
                              hipStream_t stream) {
    const float* query = (const float*)d_in[0];
    const float* qpts  = (const float*)d_in[1];
    const float* inp   = (const float*)d_in[2];
    const float* ipts  = (const float*)d_in[3];
    const float* Wv    = (const float*)d_in[4];
    const float* bv    = (const float*)d_in[5];
    const float* Ws    = (const float*)d_in[6];
    const float* bs    = (const float*)d_in[7];
    const float* Wa    = (const float*)d_in[8];
    const float* ba    = (const float*)d_in[9];
    const float* Wo    = (const float*)d_in[10];
    const float* bo    = (const float*)d_in[11];
    float* out = (float*)d_out;

    // workspace layout (floats): ~13 MB total
    float* ws    = (float*)d_ws;
    float* value = ws;                                        // B*LIN*CH   = 2,097,152
    float* out1  = value + (size_t)B_ * LIN * CH;             // B*LQ*CH    =   524,288
    float* S     = out1 + (size_t)B_ * LQ * CH;               // B*LQ*128   =   262,144
    float* Wsa   = S + (size_t)B_ * LQ * 128;                 // 128*CH     =    32,768
    float* bsa   = Wsa + 128 * CH;                            // 128
    float* loc   = bsa + 128;                                 // B*LQ*M*P*3 =   196,608
    float* attw  = loc + (size_t)B_ * LQ * MH * NP * 3;       // B*LQ*M*P   =    65,536
    int*   idx   = (int*)(attw + (size_t)B_ * LQ * MH * NP);  // B*LQ*M*P   =    65,536

    // 1. value projection: (8192,256) @ (256,256)^T
    gemm_nt_bias<<<dim3(128, 4), 256, 0, stream>>>(inp, Wv, bv, value, 8192, 256, 256);
    // 2. pack [Ws;Wa] -> (128,256)
    pack_wsa<<<128, 256, 0, stream>>>(Ws, bs, Wa, ba, Wsa, bsa);
    // 3. sampling offsets + attn logits: (2048,256) @ (128,256)^T
    gemm_nt_bias<<<dim3(32, 2), 256, 0, stream>>>(query, Wsa, bsa, S, 2048, 128, 256);
    // 4. sampling locations + softmax weights
    loc_attw_kernel<<<64, 256, 0, stream>>>(S, qpts, loc, attw);
    // 5. fused KNN argmin (never materializes the 1 GB distance matrix)
    knn_kernel<<<512, 128, 0, stream>>>(loc, ipts, idx);
    // 6. gather + weighted head merge
    gather_kernel<<<B_ * LQ, 256, 0, stream>>>(value, attw, idx, out1);
    // 7. output projection: (2048,256) @ (256,256)^T
    gemm_nt_bias<<<dim3(32, 4), 256, 0, stream>>>(out1, Wo, bo, out, 2048, 256, 256);
}

// Round 2
// 186.120 us; speedup vs baseline: 1.4492x; 1.4492x over previous
//
#include <hip/hip_runtime.h>

#define B_   2
#define LQ   1024
#define LIN  4096
#define CH   256
#define MH   8
#define NP   4

#define NPTS    (B_ * LQ * MH * NP)   // 65536 sampling points
#define SLICES  4
#define SLICE_LEN (LIN / SLICES)      // 1024 candidates per slice
#define KNN_THREADS 256
#define PTS_PER_BLOCK (KNN_THREADS * 2) // 512 sampling points per block

// ---------------------------------------------------------------------------
// C[M,N] = A[M,K] * B[N,K]^T + bias[N]   (both operands K-contiguous, "NT")
// 64x64 block tile, BK=16, 256 threads, 4x4 micro-tile per thread.
// ---------------------------------------------------------------------------
__global__ __launch_bounds__(256)
void gemm_nt_bias(const float* __restrict__ A, const float* __restrict__ B,
                  const float* __restrict__ bias, float* __restrict__ C,
                  int M, int N, int K) {
    __shared__ float As[16][64];
    __shared__ float Bs[16][64];
    const int tid = threadIdx.x;
    const int bm  = blockIdx.x * 64;
    const int bn  = blockIdx.y * 64;
    const int tx  = tid & 15;        // col group
    const int ty  = tid >> 4;        // row group
    const int lm  = tid >> 2;        // staging row within tile
    const int lk  = (tid & 3) << 2;  // staging k offset (0,4,8,12)

    const float* Ap = A + (size_t)(bm + lm) * K + lk;
    const float* Bp = B + (size_t)(bn + lm) * K + lk;

    float acc[4][4] = {};
    for (int k0 = 0; k0 < K; k0 += 16) {
        float4 av = *reinterpret_cast<const float4*>(Ap + k0);
        float4 bv = *reinterpret_cast<const float4*>(Bp + k0);
        __syncthreads();
        As[lk + 0][lm] = av.x; As[lk + 1][lm] = av.y;
        As[lk + 2][lm] = av.z; As[lk + 3][lm] = av.w;
        Bs[lk + 0][lm] = bv.x; Bs[lk + 1][lm] = bv.y;
        Bs[lk + 2][lm] = bv.z; Bs[lk + 3][lm] = bv.w;
        __syncthreads();
#pragma unroll
        for (int k = 0; k < 16; ++k) {
            float4 a = *reinterpret_cast<const float4*>(&As[k][ty << 2]);
            float4 b = *reinterpret_cast<const float4*>(&Bs[k][tx << 2]);
            float ar[4] = {a.x, a.y, a.z, a.w};
            float br[4] = {b.x, b.y, b.z, b.w};
#pragma unroll
            for (int i = 0; i < 4; ++i)
#pragma unroll
                for (int j = 0; j < 4; ++j)
                    acc[i][j] = fmaf(ar[i], br[j], acc[i][j]);
        }
    }
#pragma unroll
    for (int i = 0; i < 4; ++i) {
        const int row = bm + (ty << 2) + i;
        const int col = bn + (tx << 2);
        float4 c;
        c.x = acc[i][0] + bias[col + 0];
        c.y = acc[i][1] + bias[col + 1];
        c.z = acc[i][2] + bias[col + 2];
        c.w = acc[i][3] + bias[col + 3];
        *reinterpret_cast<float4*>(C + (size_t)row * N + col) = c;
    }
}

// ---------------------------------------------------------------------------
// Pack Ws(96x256) and Wa(32x256) (+biases) into one 128x256 weight matrix.
// ---------------------------------------------------------------------------
__global__ void pack_wsa(const float* __restrict__ Ws, const float* __restrict__ bs,
                         const float* __restrict__ Wa, const float* __restrict__ ba,
                         float* __restrict__ Wsa, float* __restrict__ bsa) {
    int j = blockIdx.x, k = threadIdx.x;
    Wsa[j * CH + k] = (j < 96) ? Ws[j * CH + k] : Wa[(j - 96) * CH + k];
    if (k == 0) bsa[j] = (j < 96) ? bs[j] : ba[j - 96];
}

// ---------------------------------------------------------------------------
// From S = query @ [Ws;Wa]^T + [bs;ba]  (2048 x 128):
//   loc[b,q,m,p,:]  = query_points[b,q,:] + S[row][m*12 + p*3 + e]
//   attw[b,q,m,p]   = softmax_p(S[row][96 + m*4 + p])
// ---------------------------------------------------------------------------
__global__ __launch_bounds__(256)
void loc_attw_kernel(const float* __restrict__ S, const float* __restrict__ qpts,
                     float* __restrict__ loc, float* __restrict__ attw) {
    int t = blockIdx.x * 256 + threadIdx.x;    // [0, 16384)
    int m = t & 7;
    int r = t >> 3;                            // row in [0, 2048)
    const float* Sr = S + (size_t)r * 128;
    float q0 = qpts[r * 3 + 0], q1 = qpts[r * 3 + 1], q2 = qpts[r * 3 + 2];
#pragma unroll
    for (int p = 0; p < NP; ++p) {
        size_t o = ((size_t)(r * MH + m) * NP + p) * 3;
        loc[o + 0] = q0 + Sr[m * 12 + p * 3 + 0];
        loc[o + 1] = q1 + Sr[m * 12 + p * 3 + 1];
        loc[o + 2] = q2 + Sr[m * 12 + p * 3 + 2];
    }
    float l0 = Sr[96 + m * 4 + 0], l1 = Sr[96 + m * 4 + 1];
    float l2 = Sr[96 + m * 4 + 2], l3 = Sr[96 + m * 4 + 3];
    float mx = fmaxf(fmaxf(l0, l1), fmaxf(l2, l3));
    float e0 = expf(l0 - mx), e1 = expf(l1 - mx);
    float e2 = expf(l2 - mx), e3 = expf(l3 - mx);
    float inv = 1.0f / (e0 + e1 + e2 + e3);
    size_t ao = (size_t)(r * MH + m) * NP;
    attw[ao + 0] = e0 * inv; attw[ao + 1] = e1 * inv;
    attw[ao + 2] = e2 * inv; attw[ao + 3] = e3 * inv;
}

// ---------------------------------------------------------------------------
// KNN partial argmin. Grid: (NPTS/PTS_PER_BLOCK, SLICES). Each block scans
// one 1024-candidate slice (staged once in 16 KB LDS) for 512 sampling
// points; each thread owns 2 points x 4 independent trackers (8 min-chains
// of ILP; every float4 LDS broadcast read feeds 12 VALU ops).
// 2048 waves total -> 8 waves/CU (vs 4 before: the round-1 kernel was
// grid-limited to 1 wave/SIMD and latency-bound at 42% VALUBusy).
// ---------------------------------------------------------------------------
__global__ __launch_bounds__(KNN_THREADS)
void knn_partial_kernel(const float* __restrict__ loc, const float* __restrict__ ipts,
                        float* __restrict__ pd, int* __restrict__ pi) {
    __shared__ float4 pts[SLICE_LEN];
    const int slice = blockIdx.y;
    const int t0    = slice * SLICE_LEN;          // candidate base (global idx)
    const int pt0   = blockIdx.x * PTS_PER_BLOCK; // sampling-point base
    const int b     = pt0 >> 15;                  // 32768 points per batch

    // stage slice: 1024 candidates as float4(x,y,z,|v|^2); thread t stages
    // candidates 4t..4t+3 (12 contiguous floats = 3 aligned float4 loads)
    {
        const float* sp = ipts + ((size_t)b * LIN + t0) * 3 + threadIdx.x * 12;
        float4 u0 = *reinterpret_cast<const float4*>(sp + 0);
        float4 u1 = *reinterpret_cast<const float4*>(sp + 4);
        float4 u2 = *reinterpret_cast<const float4*>(sp + 8);
        float xs[4] = {u0.x, u0.w, u1.z, u2.y};
        float ys[4] = {u0.y, u1.x, u1.w, u2.z};
        float zs[4] = {u0.z, u1.y, u2.x, u2.w};
#pragma unroll
        for (int i = 0; i < 4; ++i) {
            float nrm = fmaf(zs[i], zs[i], fmaf(ys[i], ys[i], xs[i] * xs[i]));
            pts[threadIdx.x * 4 + i] = make_float4(xs[i], ys[i], zs[i], nrm);
        }
    }

    // two sampling points per thread
    const int pA = pt0 + threadIdx.x;
    const int pB = pA + KNN_THREADS;
    float ax2 = -2.f * loc[(size_t)pA * 3 + 0];
    float ay2 = -2.f * loc[(size_t)pA * 3 + 1];
    float az2 = -2.f * loc[(size_t)pA * 3 + 2];
    float bx2 = -2.f * loc[(size_t)pB * 3 + 0];
    float by2 = -2.f * loc[(size_t)pB * 3 + 1];
    float bz2 = -2.f * loc[(size_t)pB * 3 + 2];

    float bdA[4], bdB[4];
    int   biA[4], biB[4];
#pragma unroll
    for (int j = 0; j < 4; ++j) {
        bdA[j] = bdB[j] = 1e30f;
        biA[j] = biB[j] = t0;
    }

    __syncthreads();
#pragma unroll 2
    for (int l = 0; l < SLICE_LEN; l += 4) {
#pragma unroll
        for (int j = 0; j < 4; ++j) {
            float4 p = pts[l + j];
            float dA = fmaf(ax2, p.x, fmaf(ay2, p.y, fmaf(az2, p.z, p.w)));
            float dB = fmaf(bx2, p.x, fmaf(by2, p.y, fmaf(bz2, p.z, p.w)));
            if (dA < bdA[j]) { bdA[j] = dA; biA[j] = t0 + l + j; }
            if (dB < bdB[j]) { bdB[j] = dB; biB[j] = t0 + l + j; }
        }
    }

    // lexicographic (d, i) tracker merge -> slice-first-minimum
    float dA = bdA[0]; int iA = biA[0];
    float dB = bdB[0]; int iB = biB[0];
#pragma unroll
    for (int j = 1; j < 4; ++j) {
        if (bdA[j] < dA || (bdA[j] == dA && biA[j] < iA)) { dA = bdA[j]; iA = biA[j]; }
        if (bdB[j] < dB || (bdB[j] == dB && biB[j] < iB)) { dB = bdB[j]; iB = biB[j]; }
    }
    size_t so = (size_t)slice * NPTS;
    pd[so + pA] = dA;  pi[so + pA] = iA;
    pd[so + pB] = dB;  pi[so + pB] = iB;
}

// ---------------------------------------------------------------------------
// Merge the SLICES partial argmins; ties -> lowest global index (jnp.argmin).
// ---------------------------------------------------------------------------
__global__ __launch_bounds__(256)
void knn_merge_kernel(const float* __restrict__ pd, const int* __restrict__ pi,
                      int* __restrict__ idx) {
    int g = blockIdx.x * 256 + threadIdx.x;    // [0, NPTS)
    float bd = pd[g];
    int   bi = pi[g];
#pragma unroll
    for (int s = 1; s < SLICES; ++s) {
        float d = pd[(size_t)s * NPTS + g];
        int   i = pi[(size_t)s * NPTS + g];
        if (d < bd || (d == bd && i < bi)) { bd = d; bi = i; }
    }
    idx[g] = bi;
}

// ---------------------------------------------------------------------------
// out1[b,q,c] = sum_p attw[b,q,m,p] * value[b, idx[b,q,m,p], m, d]   (c=m*32+d)
// ---------------------------------------------------------------------------
__global__ __launch_bounds__(256)
void gather_kernel(const float* __restrict__ value, const float* __restrict__ attw,
                   const int* __restrict__ idx, float* __restrict__ out1) {
    int bq = blockIdx.x;                 // b*LQ + q
    int c  = threadIdx.x;
    int m  = c >> 5;
    int b  = bq >> 10;
    size_t base = ((size_t)bq * MH + m) * NP;
    const float* vb = value + (size_t)b * LIN * CH;
    float acc = 0.f;
#pragma unroll
    for (int p = 0; p < NP; ++p) {
        int   i = idx[base + p];
        float w = attw[base + p];
        acc = fmaf(w, vb[(size_t)i * CH + c], acc);
    }
    out1[(size_t)bq * CH + c] = acc;
}

// ---------------------------------------------------------------------------
extern "C" void kernel_launch(void* const* d_in, const int* in_sizes, int n_in,
                              void* d_out, int out_size, void* d_ws, size_t ws_size,
                              hipStream_t stream) {
    const float* query = (const float*)d_in[0];
    const float* qpts  = (const float*)d_in[1];
    const float* inp   = (const float*)d_in[2];
    const float* ipts  = (const float*)d_in[3];
    const float* Wv    = (const float*)d_in[4];
    const float* bv    = (const float*)d_in[5];
    const float* Ws    = (const float*)d_in[6];
    const float* bs    = (const float*)d_in[7];
    const float* Wa    = (const float*)d_in[8];
    const float* ba    = (const float*)d_in[9];
    const float* Wo    = (const float*)d_in[10];
    const float* bo    = (const float*)d_in[11];
    float* out = (float*)d_out;

    // workspace layout (floats): ~15.5 MB total
    float* ws    = (float*)d_ws;
    float* value = ws;                                        // B*LIN*CH   = 2,097,152
    float* out1  = value + (size_t)B_ * LIN * CH;             // B*LQ*CH    =   524,288
    float* S     = out1 + (size_t)B_ * LQ * CH;               // B*LQ*128   =   262,144
    float* Wsa   = S + (size_t)B_ * LQ * 128;                 // 128*CH     =    32,768
    float* bsa   = Wsa + 128 * CH;                            // 128
    float* loc   = bsa + 128;                                 // NPTS*3     =   196,608
    float* attw  = loc + (size_t)NPTS * 3;                    // NPTS       =    65,536
    float* pd    = attw + (size_t)NPTS;                       // SLICES*NPTS=   262,144
    int*   pi    = (int*)(pd + (size_t)SLICES * NPTS);        // SLICES*NPTS=   262,144
    int*   idx   = pi + (size_t)SLICES * NPTS;                // NPTS       =    65,536

    // 1. value projection: (8192,256) @ (256,256)^T
    gemm_nt_bias<<<dim3(128, 4), 256, 0, stream>>>(inp, Wv, bv, value, 8192, 256, 256);
    // 2. pack [Ws;Wa] -> (128,256)
    pack_wsa<<<128, 256, 0, stream>>>(Ws, bs, Wa, ba, Wsa, bsa);
    // 3. sampling offsets + attn logits: (2048,256) @ (128,256)^T
    gemm_nt_bias<<<dim3(32, 2), 256, 0, stream>>>(query, Wsa, bsa, S, 2048, 128, 256);
    // 4. sampling locations + softmax weights
    loc_attw_kernel<<<64, 256, 0, stream>>>(S, qpts, loc, attw);
    // 5. fused KNN argmin, 4-way candidate split (never materializes the
    //    1 GB distance matrix; 2048 waves for latency hiding)
    knn_partial_kernel<<<dim3(NPTS / PTS_PER_BLOCK, SLICES), KNN_THREADS, 0, stream>>>(
        loc, ipts, pd, pi);
    knn_merge_kernel<<<NPTS / 256, 256, 0, stream>>>(pd, pi, idx);
    // 6. gather + weighted head merge
    gather_kernel<<<B_ * LQ, 256, 0, stream>>>(value, attw, idx, out1);
    // 7. output projection: (2048,256) @ (256,256)^T
    gemm_nt_bias<<<dim3(32, 4), 256, 0, stream>>>(out1, Wo, bo, out, 2048, 256, 256);
}

// Round 3
// 170.591 us; speedup vs baseline: 1.5811x; 1.0910x over previous
//
#include <hip/hip_runtime.h>

#define B_   2
#define LQ   1024
#define LIN  4096
#define CH   256
#define MH   8
#define NP   4

#define NPTS      (B_ * LQ * MH * NP)   // 65536 sampling points
#define SLICES    16
#define SLICE_LEN (LIN / SLICES)        // 256 candidates per slice
#define KNN_PPT   4                     // points per thread
#define KNN_THREADS 256

// ---------------------------------------------------------------------------
// C[M,N] = A[M,K] * B[N,K]^T + bias[N]  ("NT", both K-contiguous)
// 64x64 tile, BK=32, 256 threads, 4x4 micro-tile, register prefetch of the
// next global tile so HBM latency hides under the 512-fma compute phase.
// ---------------------------------------------------------------------------
__global__ __launch_bounds__(256)
void gemm_nt_bias(const float* __restrict__ A, const float* __restrict__ B,
                  const float* __restrict__ bias, float* __restrict__ C,
                  int M, int N, int K) {
    __shared__ float As[32][64];
    __shared__ float Bs[32][64];
    const int tid = threadIdx.x;
    const int bm  = blockIdx.x * 64;
    const int bn  = blockIdx.y * 64;
    const int tx  = tid & 15;         // col group (4 cols)
    const int ty  = tid >> 4;         // row group (4 rows)
    const int lr  = tid >> 2;         // staging row 0..63
    const int lk  = (tid & 3) * 8;    // staging k offset {0,8,16,24}

    const float* Ap = A + (size_t)(bm + lr) * K + lk;
    const float* Bp = B + (size_t)(bn + lr) * K + lk;

    float4 a0 = *reinterpret_cast<const float4*>(Ap);
    float4 a1 = *reinterpret_cast<const float4*>(Ap + 4);
    float4 b0 = *reinterpret_cast<const float4*>(Bp);
    float4 b1 = *reinterpret_cast<const float4*>(Bp + 4);

    float acc[4][4] = {};
    for (int k0 = 0; k0 < K; k0 += 32) {
        __syncthreads();
        As[lk + 0][lr] = a0.x; As[lk + 1][lr] = a0.y;
        As[lk + 2][lr] = a0.z; As[lk + 3][lr] = a0.w;
        As[lk + 4][lr] = a1.x; As[lk + 5][lr] = a1.y;
        As[lk + 6][lr] = a1.z; As[lk + 7][lr] = a1.w;
        Bs[lk + 0][lr] = b0.x; Bs[lk + 1][lr] = b0.y;
        Bs[lk + 2][lr] = b0.z; Bs[lk + 3][lr] = b0.w;
        Bs[lk + 4][lr] = b1.x; Bs[lk + 5][lr] = b1.y;
        Bs[lk + 6][lr] = b1.z; Bs[lk + 7][lr] = b1.w;
        __syncthreads();
        if (k0 + 32 < K) {   // prefetch next tile into registers
            a0 = *reinterpret_cast<const float4*>(Ap + k0 + 32);
            a1 = *reinterpret_cast<const float4*>(Ap + k0 + 36);
            b0 = *reinterpret_cast<const float4*>(Bp + k0 + 32);
            b1 = *reinterpret_cast<const float4*>(Bp + k0 + 36);
        }
#pragma unroll
        for (int k = 0; k < 32; ++k) {
            float4 a = *reinterpret_cast<const float4*>(&As[k][ty << 2]);
            float4 b = *reinterpret_cast<const float4*>(&Bs[k][tx << 2]);
            float ar[4] = {a.x, a.y, a.z, a.w};
            float br[4] = {b.x, b.y, b.z, b.w};
#pragma unroll
            for (int i = 0; i < 4; ++i)
#pragma unroll
                for (int j = 0; j < 4; ++j)
                    acc[i][j] = fmaf(ar[i], br[j], acc[i][j]);
        }
    }
#pragma unroll
    for (int i = 0; i < 4; ++i) {
        const int row = bm + (ty << 2) + i;
        const int col = bn + (tx << 2);
        float4 c;
        c.x = acc[i][0] + bias[col + 0];
        c.y = acc[i][1] + bias[col + 1];
        c.z = acc[i][2] + bias[col + 2];
        c.w = acc[i][3] + bias[col + 3];
        *reinterpret_cast<float4*>(C + (size_t)row * N + col) = c;
    }
}

// ---------------------------------------------------------------------------
// Fused S-path: S = query @ [Ws;Wa]^T + [bs;ba] (2048x128), then directly
//   loc[b,q,m,p,:] = query_points + S[row][m*12+p*3+e]
//   attw[b,q,m,p]  = softmax_p(S[row][96+m*4+p])
// One block = 64 rows x all 128 cols (full rows -> epilogue is local).
// 256 threads, 4x8 micro-tile, BK=16. Never materializes S in global.
// ---------------------------------------------------------------------------
__global__ __launch_bounds__(256)
void gemm_s_fused(const float* __restrict__ query,
                  const float* __restrict__ Ws, const float* __restrict__ bs,
                  const float* __restrict__ Wa, const float* __restrict__ ba,
                  const float* __restrict__ qpts,
                  float* __restrict__ loc, float* __restrict__ attw) {
    __shared__ float As[16][64];     // 4 KB
    __shared__ float Bs[16][128];    // 8 KB
    __shared__ float Ss[64][132];    // 33 KB (padded)
    const int tid = threadIdx.x;
    const int rowbase = blockIdx.x * 64;
    const int tx = tid & 15;         // col group (8 cols: tx*8)
    const int ty = tid >> 4;         // row group (4 rows: ty*4)

    // A staging coords: row lr, k-offset lka (float4)
    const int lr  = tid >> 2;
    const int lka = (tid & 3) * 4;
    const float* Ap = query + (size_t)(rowbase + lr) * CH + lka;
    // B staging coords: weight row n (virtual [Ws;Wa] row), 8 k per thread
    const int n   = tid >> 1;
    const int lkb = (tid & 1) * 8;
    const float* Wrow = ((n < 96) ? (Ws + (size_t)n * CH)
                                  : (Wa + (size_t)(n - 96) * CH)) + lkb;
    // per-thread bias for cols tx*8..tx*8+7
    float bj[8];
#pragma unroll
    for (int j = 0; j < 8; ++j) {
        int col = tx * 8 + j;
        bj[j] = (col < 96) ? bs[col] : ba[col - 96];
    }

    float4 a0 = *reinterpret_cast<const float4*>(Ap);
    float4 b0 = *reinterpret_cast<const float4*>(Wrow);
    float4 b1 = *reinterpret_cast<const float4*>(Wrow + 4);

    float acc[4][8] = {};
    for (int k0 = 0; k0 < CH; k0 += 16) {
        __syncthreads();
        As[lka + 0][lr] = a0.x; As[lka + 1][lr] = a0.y;
        As[lka + 2][lr] = a0.z; As[lka + 3][lr] = a0.w;
        Bs[lkb + 0][n] = b0.x; Bs[lkb + 1][n] = b0.y;
        Bs[lkb + 2][n] = b0.z; Bs[lkb + 3][n] = b0.w;
        Bs[lkb + 4][n] = b1.x; Bs[lkb + 5][n] = b1.y;
        Bs[lkb + 6][n] = b1.z; Bs[lkb + 7][n] = b1.w;
        __syncthreads();
        if (k0 + 16 < CH) {
            a0 = *reinterpret_cast<const float4*>(Ap + k0 + 16);
            b0 = *reinterpret_cast<const float4*>(Wrow + k0 + 16);
            b1 = *reinterpret_cast<const float4*>(Wrow + k0 + 20);
        }
#pragma unroll
        for (int k = 0; k < 16; ++k) {
            float4 a  = *reinterpret_cast<const float4*>(&As[k][ty << 2]);
            float4 v0 = *reinterpret_cast<const float4*>(&Bs[k][tx * 8]);
            float4 v1 = *reinterpret_cast<const float4*>(&Bs[k][tx * 8 + 4]);
            float ar[4] = {a.x, a.y, a.z, a.w};
            float br[8] = {v0.x, v0.y, v0.z, v0.w, v1.x, v1.y, v1.z, v1.w};
#pragma unroll
            for (int i = 0; i < 4; ++i)
#pragma unroll
                for (int j = 0; j < 8; ++j)
                    acc[i][j] = fmaf(ar[i], br[j], acc[i][j]);
        }
    }

    // stash S tile (with bias) in LDS, then do loc/softmax epilogue locally
    __syncthreads();
#pragma unroll
    for (int i = 0; i < 4; ++i)
#pragma unroll
        for (int j = 0; j < 8; ++j)
            Ss[ty * 4 + i][tx * 8 + j] = acc[i][j] + bj[j];
    __syncthreads();

#pragma unroll
    for (int half = 0; half < 2; ++half) {
        int u   = tid + half * 256;        // 512 units = 64 rows x 8 heads
        int row = u >> 3;
        int m   = u & 7;
        int r   = rowbase + row;           // global row (b*LQ+q)
        const float* Sr = Ss[row];
        float q0 = qpts[r * 3 + 0], q1 = qpts[r * 3 + 1], q2 = qpts[r * 3 + 2];
#pragma unroll
        for (int p = 0; p < NP; ++p) {
            size_t o = ((size_t)(r * MH + m) * NP + p) * 3;
            loc[o + 0] = q0 + Sr[m * 12 + p * 3 + 0];
            loc[o + 1] = q1 + Sr[m * 12 + p * 3 + 1];
            loc[o + 2] = q2 + Sr[m * 12 + p * 3 + 2];
        }
        float l0 = Sr[96 + m * 4 + 0], l1 = Sr[96 + m * 4 + 1];
        float l2 = Sr[96 + m * 4 + 2], l3 = Sr[96 + m * 4 + 3];
        float mx = fmaxf(fmaxf(l0, l1), fmaxf(l2, l3));
        float e0 = expf(l0 - mx), e1 = expf(l1 - mx);
        float e2 = expf(l2 - mx), e3 = expf(l3 - mx);
        float inv = 1.0f / (e0 + e1 + e2 + e3);
        size_t ao = (size_t)(r * MH + m) * NP;
        attw[ao + 0] = e0 * inv; attw[ao + 1] = e1 * inv;
        attw[ao + 2] = e2 * inv; attw[ao + 3] = e3 * inv;
    }
}

// ---------------------------------------------------------------------------
// KNN argmin via packed-key atomicMin. Grid (NPTS/1024, SLICES).
// Each block: 256-candidate slice staged once in LDS as float4(x,y,z,|v|^2);
// each thread owns 4 sampling points (one ds_read_b128 feeds 24 VALU ops,
// vs 12 in round 2 -> LDS pipe cost halves) x 2 trackers (8 ILP chains).
// Result merged with key = (order-preserving-uint(d) << 32) | idx:
// bit-exact d ordering, equal-d ties -> lowest idx (= jnp.argmin first-min),
// deterministic under any atomic arrival order.
// ---------------------------------------------------------------------------
__global__ __launch_bounds__(KNN_THREADS)
void knn_partial_kernel(const float* __restrict__ loc, const float* __restrict__ ipts,
                        unsigned long long* __restrict__ keys) {
    __shared__ float4 pts[SLICE_LEN];
    const int slice = blockIdx.y;
    const int t0    = slice * SLICE_LEN;
    const int pt0   = blockIdx.x * (KNN_THREADS * KNN_PPT);
    const int b     = pt0 >> 15;                 // 32768 points per batch

    {   // stage: one candidate per thread
        const float* sp = ipts + ((size_t)b * LIN + t0 + threadIdx.x) * 3;
        float x = sp[0], y = sp[1], z = sp[2];
        pts[threadIdx.x] = make_float4(x, y, z, fmaf(z, z, fmaf(y, y, x * x)));
    }

    float cx[KNN_PPT], cy[KNN_PPT], cz[KNN_PPT];
#pragma unroll
    for (int i = 0; i < KNN_PPT; ++i) {
        int p = pt0 + threadIdx.x + i * KNN_THREADS;
        cx[i] = -2.f * loc[(size_t)p * 3 + 0];
        cy[i] = -2.f * loc[(size_t)p * 3 + 1];
        cz[i] = -2.f * loc[(size_t)p * 3 + 2];
    }

    float bd[KNN_PPT][2];
    int   bi[KNN_PPT][2];
#pragma unroll
    for (int i = 0; i < KNN_PPT; ++i) {
        bd[i][0] = bd[i][1] = 1e30f;
        bi[i][0] = bi[i][1] = t0;
    }

    __syncthreads();
#pragma unroll 4
    for (int l = 0; l < SLICE_LEN; l += 2) {
        float4 p0 = pts[l + 0];
        float4 p1 = pts[l + 1];
#pragma unroll
        for (int i = 0; i < KNN_PPT; ++i) {
            float d0 = fmaf(cx[i], p0.x, fmaf(cy[i], p0.y, fmaf(cz[i], p0.z, p0.w)));
            float d1 = fmaf(cx[i], p1.x, fmaf(cy[i], p1.y, fmaf(cz[i], p1.z, p1.w)));
            if (d0 < bd[i][0]) { bd[i][0] = d0; bi[i][0] = t0 + l; }
            if (d1 < bd[i][1]) { bd[i][1] = d1; bi[i][1] = t0 + l + 1; }
        }
    }

#pragma unroll
    for (int i = 0; i < KNN_PPT; ++i) {
        float d = bd[i][0]; int ix = bi[i][0];
        if (bd[i][1] < d || (bd[i][1] == d && bi[i][1] < ix)) { d = bd[i][1]; ix = bi[i][1]; }
        // order-preserving float->uint (d can be negative: no |s|^2 term)
        unsigned int ub = __float_as_uint(d);
        unsigned int k32 = ub ^ (((unsigned int)((int)ub >> 31)) | 0x80000000u);
        unsigned long long key = ((unsigned long long)k32 << 32) | (unsigned int)ix;
        int p = pt0 + threadIdx.x + i * KNN_THREADS;
        atomicMin(&keys[p], key);
    }
}

// ---------------------------------------------------------------------------
// out1[b,q,c] = sum_p attw[b,q,m,p] * value[b, idx[b,q,m,p], m, d]  (c=m*32+d)
// ---------------------------------------------------------------------------
__global__ __launch_bounds__(256)
void gather_kernel(const float* __restrict__ value, const float* __restrict__ attw,
                   const unsigned long long* __restrict__ keys,
                   float* __restrict__ out1) {
    int bq = blockIdx.x;                 // b*LQ + q
    int c  = threadIdx.x;
    int m  = c >> 5;
    int b  = bq >> 10;
    size_t base = ((size_t)bq * MH + m) * NP;
    const float* vb = value + (size_t)b * LIN * CH;
    float acc = 0.f;
#pragma unroll
    for (int p = 0; p < NP; ++p) {
        int   i = (int)(keys[base + p] & 0xFFFFFFFFull);
        float w = attw[base + p];
        acc = fmaf(w, vb[(size_t)i * CH + c], acc);
    }
    out1[(size_t)bq * CH + c] = acc;
}

// ---------------------------------------------------------------------------
extern "C" void kernel_launch(void* const* d_in, const int* in_sizes, int n_in,
                              void* d_out, int out_size, void* d_ws, size_t ws_size,
                              hipStream_t stream) {
    const float* query = (const float*)d_in[0];
    const float* qpts  = (const float*)d_in[1];
    const float* inp   = (const float*)d_in[2];
    const float* ipts  = (const float*)d_in[3];
    const float* Wv    = (const float*)d_in[4];
    const float* bv    = (const float*)d_in[5];
    const float* Ws    = (const float*)d_in[6];
    const float* bs    = (const float*)d_in[7];
    const float* Wa    = (const float*)d_in[8];
    const float* ba    = (const float*)d_in[9];
    const float* Wo    = (const float*)d_in[10];
    const float* bo    = (const float*)d_in[11];
    float* out = (float*)d_out;

    // workspace layout: ~11.5 MB
    float* ws    = (float*)d_ws;
    float* value = ws;                                        // B*LIN*CH   = 2,097,152 f
    float* out1  = value + (size_t)B_ * LIN * CH;             // B*LQ*CH    =   524,288 f
    float* loc   = out1 + (size_t)B_ * LQ * CH;               // NPTS*3     =   196,608 f
    float* attw  = loc + (size_t)NPTS * 3;                    // NPTS       =    65,536 f
    unsigned long long* keys =
        (unsigned long long*)(attw + (size_t)NPTS);           // NPTS       =    65,536 u64

    // 0. init argmin keys to +inf
    hipMemsetAsync(keys, 0xFF, (size_t)NPTS * sizeof(unsigned long long), stream);
    // 1. value projection: (8192,256) @ (256,256)^T
    gemm_nt_bias<<<dim3(128, 4), 256, 0, stream>>>(inp, Wv, bv, value, 8192, 256, 256);
    // 2. fused offsets+logits GEMM -> sampling locations + softmax weights
    gemm_s_fused<<<32, 256, 0, stream>>>(query, Ws, bs, Wa, ba, qpts, loc, attw);
    // 3. fused KNN argmin (atomicMin packed keys; no distance matrix)
    knn_partial_kernel<<<dim3(NPTS / (KNN_THREADS * KNN_PPT), SLICES),
                         KNN_THREADS, 0, stream>>>(loc, ipts, keys);
    // 4. gather + weighted head merge
    gather_kernel<<<B_ * LQ, 256, 0, stream>>>(value, attw, keys, out1);
    // 5. output projection: (2048,256) @ (256,256)^T
    gemm_nt_bias<<<dim3(32, 4), 256, 0, stream>>>(out1, Wo, bo, out, 2048, 256, 256);
}

// Round 4
// 160.721 us; speedup vs baseline: 1.6782x; 1.0614x over previous
//
#include <hip/hip_runtime.h>

#define B_   2
#define LQ   1024
#define LIN  4096
#define CH   256
#define MH   8
#define NP   4
#define NROW (B_ * LQ)                  // 2048 (b,q) rows
#define NPTS (NROW * MH * NP)           // 65536 sampling points

#define SLICES    16
#define SLICE_LEN (LIN / SLICES)        // 256 candidates per slice
#define KNN_PPT   4
#define KNN_THREADS 256

// LDS row-swizzle: element (r,k) stored at [r][k ^ SWZ(r)], pitch = pad to
// 16B-aligned rows; SWZ is 4-aligned so b128 k-chunks stay contiguous and
// column-frag reads across 8 row-groups land in distinct banks (<=2-way).
#define SWZ(r) ((((r) >> 2) & 7) << 2)

// ---------------------------------------------------------------------------
// Fused S-path: S = query @ [Ws;Wa]^T + [bs;ba] (2048 x 128), then directly
//   loc[b,q,m,p,:] = query_points + S[row][m*12+p*3+e]
//   attw[b,q,m,p]  = softmax_p(S[row][96+m*4+p])
//   keys[b,q,m,p]  = u64 max (argmin identity for the knn atomicMin pass)
// One block = 64 rows x all 128 cols. 256 threads, 4x8 micro-tile, BK=16.
// ---------------------------------------------------------------------------
__global__ __launch_bounds__(256)
void gemm_s_fused(const float* __restrict__ query,
                  const float* __restrict__ Ws, const float* __restrict__ bs,
                  const float* __restrict__ Wa, const float* __restrict__ ba,
                  const float* __restrict__ qpts,
                  float* __restrict__ loc, float* __restrict__ attw,
                  unsigned long long* __restrict__ keys) {
    __shared__ float As[16][64];
    __shared__ float Bs[16][128];
    __shared__ float Ss[64][132];
    const int tid = threadIdx.x;
    const int rowbase = blockIdx.x * 64;
    const int tx = tid & 15;
    const int ty = tid >> 4;

    const int lr  = tid >> 2;
    const int lka = (tid & 3) * 4;
    const float* Ap = query + (size_t)(rowbase + lr) * CH + lka;
    const int n   = tid >> 1;
    const int lkb = (tid & 1) * 8;
    const float* Wrow = ((n < 96) ? (Ws + (size_t)n * CH)
                                  : (Wa + (size_t)(n - 96) * CH)) + lkb;
    float bj[8];
#pragma unroll
    for (int j = 0; j < 8; ++j) {
        int col = tx * 8 + j;
        bj[j] = (col < 96) ? bs[col] : ba[col - 96];
    }

    float4 a0 = *reinterpret_cast<const float4*>(Ap);
    float4 b0 = *reinterpret_cast<const float4*>(Wrow);
    float4 b1 = *reinterpret_cast<const float4*>(Wrow + 4);

    float acc[4][8] = {};
    for (int k0 = 0; k0 < CH; k0 += 16) {
        __syncthreads();
        As[lka + 0][lr] = a0.x; As[lka + 1][lr] = a0.y;
        As[lka + 2][lr] = a0.z; As[lka + 3][lr] = a0.w;
        Bs[lkb + 0][n] = b0.x; Bs[lkb + 1][n] = b0.y;
        Bs[lkb + 2][n] = b0.z; Bs[lkb + 3][n] = b0.w;
        Bs[lkb + 4][n] = b1.x; Bs[lkb + 5][n] = b1.y;
        Bs[lkb + 6][n] = b1.z; Bs[lkb + 7][n] = b1.w;
        __syncthreads();
        if (k0 + 16 < CH) {
            a0 = *reinterpret_cast<const float4*>(Ap + k0 + 16);
            b0 = *reinterpret_cast<const float4*>(Wrow + k0 + 16);
            b1 = *reinterpret_cast<const float4*>(Wrow + k0 + 20);
        }
#pragma unroll
        for (int k = 0; k < 16; ++k) {
            float4 a  = *reinterpret_cast<const float4*>(&As[k][ty << 2]);
            float4 v0 = *reinterpret_cast<const float4*>(&Bs[k][tx * 8]);
            float4 v1 = *reinterpret_cast<const float4*>(&Bs[k][tx * 8 + 4]);
            float ar[4] = {a.x, a.y, a.z, a.w};
            float br[8] = {v0.x, v0.y, v0.z, v0.w, v1.x, v1.y, v1.z, v1.w};
#pragma unroll
            for (int i = 0; i < 4; ++i)
#pragma unroll
                for (int j = 0; j < 8; ++j)
                    acc[i][j] = fmaf(ar[i], br[j], acc[i][j]);
        }
    }

    __syncthreads();
#pragma unroll
    for (int i = 0; i < 4; ++i)
#pragma unroll
        for (int j = 0; j < 8; ++j)
            Ss[ty * 4 + i][tx * 8 + j] = acc[i][j] + bj[j];
    __syncthreads();

#pragma unroll
    for (int half = 0; half < 2; ++half) {
        int u   = tid + half * 256;        // 512 units = 64 rows x 8 heads
        int row = u >> 3;
        int m   = u & 7;
        int r   = rowbase + row;
        const float* Sr = Ss[row];
        float q0 = qpts[r * 3 + 0], q1 = qpts[r * 3 + 1], q2 = qpts[r * 3 + 2];
#pragma unroll
        for (int p = 0; p < NP; ++p) {
            size_t o = ((size_t)(r * MH + m) * NP + p) * 3;
            loc[o + 0] = q0 + Sr[m * 12 + p * 3 + 0];
            loc[o + 1] = q1 + Sr[m * 12 + p * 3 + 1];
            loc[o + 2] = q2 + Sr[m * 12 + p * 3 + 2];
        }
        float l0 = Sr[96 + m * 4 + 0], l1 = Sr[96 + m * 4 + 1];
        float l2 = Sr[96 + m * 4 + 2], l3 = Sr[96 + m * 4 + 3];
        float mx = fmaxf(fmaxf(l0, l1), fmaxf(l2, l3));
        float e0 = expf(l0 - mx), e1 = expf(l1 - mx);
        float e2 = expf(l2 - mx), e3 = expf(l3 - mx);
        float inv = 1.0f / (e0 + e1 + e2 + e3);
        size_t ao = (size_t)(r * MH + m) * NP;
        attw[ao + 0] = e0 * inv; attw[ao + 1] = e1 * inv;
        attw[ao + 2] = e2 * inv; attw[ao + 3] = e3 * inv;
        unsigned long long* kp = keys + ao;
        kp[0] = kp[1] = kp[2] = kp[3] = 0xFFFFFFFFFFFFFFFFull;
    }
}

// ---------------------------------------------------------------------------
// KNN argmin via packed-key atomicMin (exact first-min semantics).
// ---------------------------------------------------------------------------
__global__ __launch_bounds__(KNN_THREADS)
void knn_partial_kernel(const float* __restrict__ loc, const float* __restrict__ ipts,
                        unsigned long long* __restrict__ keys) {
    __shared__ float4 pts[SLICE_LEN];
    const int slice = blockIdx.y;
    const int t0    = slice * SLICE_LEN;
    const int pt0   = blockIdx.x * (KNN_THREADS * KNN_PPT);
    const int b     = pt0 >> 15;                 // 32768 points per batch

    {
        const float* sp = ipts + ((size_t)b * LIN + t0 + threadIdx.x) * 3;
        float x = sp[0], y = sp[1], z = sp[2];
        pts[threadIdx.x] = make_float4(x, y, z, fmaf(z, z, fmaf(y, y, x * x)));
    }

    float cx[KNN_PPT], cy[KNN_PPT], cz[KNN_PPT];
#pragma unroll
    for (int i = 0; i < KNN_PPT; ++i) {
        int p = pt0 + threadIdx.x + i * KNN_THREADS;
        cx[i] = -2.f * loc[(size_t)p * 3 + 0];
        cy[i] = -2.f * loc[(size_t)p * 3 + 1];
        cz[i] = -2.f * loc[(size_t)p * 3 + 2];
    }

    float bd[KNN_PPT][2];
    int   bi[KNN_PPT][2];
#pragma unroll
    for (int i = 0; i < KNN_PPT; ++i) {
        bd[i][0] = bd[i][1] = 1e30f;
        bi[i][0] = bi[i][1] = t0;
    }

    __syncthreads();
#pragma unroll 4
    for (int l = 0; l < SLICE_LEN; l += 2) {
        float4 p0 = pts[l + 0];
        float4 p1 = pts[l + 1];
#pragma unroll
        for (int i = 0; i < KNN_PPT; ++i) {
            float d0 = fmaf(cx[i], p0.x, fmaf(cy[i], p0.y, fmaf(cz[i], p0.z, p0.w)));
            float d1 = fmaf(cx[i], p1.x, fmaf(cy[i], p1.y, fmaf(cz[i], p1.z, p1.w)));
            if (d0 < bd[i][0]) { bd[i][0] = d0; bi[i][0] = t0 + l; }
            if (d1 < bd[i][1]) { bd[i][1] = d1; bi[i][1] = t0 + l + 1; }
        }
    }

#pragma unroll
    for (int i = 0; i < KNN_PPT; ++i) {
        float d = bd[i][0]; int ix = bi[i][0];
        if (bd[i][1] < d || (bd[i][1] == d && bi[i][1] < ix)) { d = bd[i][1]; ix = bi[i][1]; }
        unsigned int ub  = __float_as_uint(d);
        unsigned int k32 = ub ^ (((unsigned int)((int)ub >> 31)) | 0x80000000u);
        unsigned long long key = ((unsigned long long)k32 << 32) | (unsigned int)ix;
        int p = pt0 + threadIdx.x + i * KNN_THREADS;
        atomicMin(&keys[p], key);
    }
}

// ---------------------------------------------------------------------------
// blend_gemm: out1_m = (sum_p attw_p * inp[idx_p]) @ Wv_m^T   (per head m)
// Exploits sum_p attw=1 linearity: replaces the full 537M-MAC value GEMM +
// gather with a 16.8M-MAC blend + 134M-MAC thin GEMM. K-split 2 -> 256
// blocks (1/CU). Blend rows land directly in swizzled k-major LDS.
// part[ks][((m*NROW + bq)*32 + d)]
// ---------------------------------------------------------------------------
__global__ __launch_bounds__(256)
void blend_gemm_kernel(const float* __restrict__ inp, const float* __restrict__ attw,
                       const unsigned long long* __restrict__ keys,
                       const float* __restrict__ Wv, float* __restrict__ part) {
    __shared__ float Ab[128][132];   // blended rows, k-major, swizzled
    __shared__ float Bs[32][132];    // Wv_m half, k-major, swizzled
    __shared__ int   ids[128][4];
    __shared__ float ats[128][4];
    const int t  = threadIdx.x;
    const int rb = blockIdx.x * 128;     // bq base
    const int m  = blockIdx.y;
    const int ks = blockIdx.z;
    const int k0 = ks * 128;

    if (t < 128) {
        size_t base = ((size_t)(rb + t) * MH + m) * NP;
#pragma unroll
        for (int p = 0; p < NP; ++p) {
            ids[t][p] = (int)(keys[base + p] & 0xFFFFFFFFull);
            ats[t][p] = attw[base + p];
        }
    }
    // stage Wv_m half: Bs[n][k ^ SWZ(n)]
#pragma unroll
    for (int pass = 0; pass < 4; ++pass) {
        int u  = pass * 256 + t;
        int nn = u >> 5;                 // 0..31
        int cg = (u & 31) * 4;           // 0..124
        float4 w = *reinterpret_cast<const float4*>(Wv + (size_t)(m * 32 + nn) * CH + k0 + cg);
        *reinterpret_cast<float4*>(&Bs[nn][cg ^ SWZ(nn)]) = w;
    }
    __syncthreads();

    // blend: Ab[row][c ^ SWZ(row)] = sum_p ats * inp[b, idx_p, k0+c]
#pragma unroll
    for (int pass = 0; pass < 16; ++pass) {
        int u   = pass * 256 + t;
        int row = u >> 5;                // 0..127
        int cg  = (u & 31) * 4;          // 0..124 (lanes -> coalesced 512B)
        int bq  = rb + row;
        const float* ib = inp + ((size_t)(bq >> 10) * LIN) * CH + k0 + cg;
        float4 a = {0.f, 0.f, 0.f, 0.f};
#pragma unroll
        for (int p = 0; p < NP; ++p) {
            float4 v = *reinterpret_cast<const float4*>(ib + (size_t)ids[row][p] * CH);
            float w = ats[row][p];
            a.x = fmaf(w, v.x, a.x); a.y = fmaf(w, v.y, a.y);
            a.z = fmaf(w, v.z, a.z); a.w = fmaf(w, v.w, a.w);
        }
        *reinterpret_cast<float4*>(&Ab[row][cg ^ SWZ(row)]) = a;
    }
    __syncthreads();

    // GEMM: 128 rows x 32 n x 128 k; micro 4x4, k-vectorized b128 frags
    const int ty = t >> 3;               // 0..31 -> rows ty*4..
    const int tx = t & 7;                // 0..7  -> cols tx*4..
    const int sA = SWZ(ty * 4);          // same for the 4 frag rows
    const int sB = SWZ(tx * 4);
    float acc[4][4] = {};
    for (int k = 0; k < 128; k += 4) {
        float4 a[4], b[4];
#pragma unroll
        for (int i = 0; i < 4; ++i)
            a[i] = *reinterpret_cast<const float4*>(&Ab[ty * 4 + i][k ^ sA]);
#pragma unroll
        for (int j = 0; j < 4; ++j)
            b[j] = *reinterpret_cast<const float4*>(&Bs[tx * 4 + j][k ^ sB]);
#pragma unroll
        for (int i = 0; i < 4; ++i)
#pragma unroll
            for (int j = 0; j < 4; ++j)
                acc[i][j] = fmaf(a[i].x, b[j].x, fmaf(a[i].y, b[j].y,
                             fmaf(a[i].z, b[j].z, fmaf(a[i].w, b[j].w, acc[i][j]))));
    }
#pragma unroll
    for (int i = 0; i < 4; ++i) {
        int bq = rb + ty * 4 + i;
        float4 c = {acc[i][0], acc[i][1], acc[i][2], acc[i][3]};
        *reinterpret_cast<float4*>(part + ((size_t)ks * MH * NROW + (size_t)m * NROW + bq) * 32 + tx * 4) = c;
    }
}

// ---------------------------------------------------------------------------
// out_gemm: out = (part0 + part1 + bv) @ Wo^T + bo   (2048 x 256, K=256)
// 64x32 tiles -> grid (32,8) = 256 blocks. A reconstructed into swizzled
// k-major LDS during staging (merges K-halves + value bias).
// ---------------------------------------------------------------------------
__global__ __launch_bounds__(256)
void out_gemm_kernel(const float* __restrict__ part, const float* __restrict__ bv,
                     const float* __restrict__ Wo, const float* __restrict__ bo,
                     float* __restrict__ out) {
    __shared__ float Ab[64][260];
    __shared__ float Bs[32][260];
    const int t  = threadIdx.x;
    const int rb = blockIdx.x * 64;      // bq base
    const int nb = blockIdx.y * 32;      // out-col base

    // stage A: Ab[row][c ^ SWZ(row)] = p0 + p1 + bv[c]
#pragma unroll
    for (int pass = 0; pass < 16; ++pass) {
        int u   = pass * 256 + t;
        int row = u >> 6;                // 0..63
        int cg  = (u & 63) * 4;          // 0..252
        int bq  = rb + row;
        int mm  = cg >> 5, d = cg & 31;
        size_t pi = ((size_t)mm * NROW + bq) * 32 + d;
        float4 v0 = *reinterpret_cast<const float4*>(part + pi);
        float4 v1 = *reinterpret_cast<const float4*>(part + (size_t)MH * NROW * 32 + pi);
        float4 bb = *reinterpret_cast<const float4*>(bv + cg);
        float4 a  = {v0.x + v1.x + bb.x, v0.y + v1.y + bb.y,
                     v0.z + v1.z + bb.z, v0.w + v1.w + bb.w};
        *reinterpret_cast<float4*>(&Ab[row][cg ^ SWZ(row)]) = a;
    }
    // stage B: Bs[n][c ^ SWZ(n)] = Wo[nb+n][c]
#pragma unroll
    for (int pass = 0; pass < 8; ++pass) {
        int u  = pass * 256 + t;
        int nn = u >> 6;                 // 0..31
        int cg = (u & 63) * 4;
        float4 w = *reinterpret_cast<const float4*>(Wo + (size_t)(nb + nn) * CH + cg);
        *reinterpret_cast<float4*>(&Bs[nn][cg ^ SWZ(nn)]) = w;
    }
    __syncthreads();

    // GEMM: 64 rows x 32 n x 256 k; micro 2x4
    const int ty = t >> 3;               // 0..31 -> rows ty*2..
    const int tx = t & 7;                // 0..7  -> cols tx*4..
    const int sA = SWZ(ty * 2);          // rows ty*2, ty*2+1 share (r>>2)
    const int sB = SWZ(tx * 4);
    float acc[2][4] = {};
    for (int k = 0; k < 256; k += 4) {
        float4 a[2], b[4];
#pragma unroll
        for (int i = 0; i < 2; ++i)
            a[i] = *reinterpret_cast<const float4*>(&Ab[ty * 2 + i][k ^ sA]);
#pragma unroll
        for (int j = 0; j < 4; ++j)
            b[j] = *reinterpret_cast<const float4*>(&Bs[tx * 4 + j][k ^ sB]);
#pragma unroll
        for (int i = 0; i < 2; ++i)
#pragma unroll
            for (int j = 0; j < 4; ++j)
                acc[i][j] = fmaf(a[i].x, b[j].x, fmaf(a[i].y, b[j].y,
                             fmaf(a[i].z, b[j].z, fmaf(a[i].w, b[j].w, acc[i][j]))));
    }
#pragma unroll
    for (int i = 0; i < 2; ++i) {
        int bq = rb + ty * 2 + i;
        int n  = nb + tx * 4;
        float4 c = {acc[i][0] + bo[n + 0], acc[i][1] + bo[n + 1],
                    acc[i][2] + bo[n + 2], acc[i][3] + bo[n + 3]};
        *reinterpret_cast<float4*>(out + (size_t)bq * CH + n) = c;
    }
}

// ---------------------------------------------------------------------------
extern "C" void kernel_launch(void* const* d_in, const int* in_sizes, int n_in,
                              void* d_out, int out_size, void* d_ws, size_t ws_size,
                              hipStream_t stream) {
    const float* query = (const float*)d_in[0];
    const float* qpts  = (const float*)d_in[1];
    const float* inp   = (const float*)d_in[2];
    const float* ipts  = (const float*)d_in[3];
    const float* Wv    = (const float*)d_in[4];
    const float* bv    = (const float*)d_in[5];
    const float* Ws    = (const float*)d_in[6];
    const float* bs    = (const float*)d_in[7];
    const float* Wa    = (const float*)d_in[8];
    const float* ba    = (const float*)d_in[9];
    const float* Wo    = (const float*)d_in[10];
    const float* bo    = (const float*)d_in[11];
    float* out = (float*)d_out;

    // workspace layout (~5.8 MB)
    float* ws   = (float*)d_ws;
    float* loc  = ws;                                   // NPTS*3      = 196,608 f
    float* attw = loc + (size_t)NPTS * 3;               // NPTS        =  65,536 f
    unsigned long long* keys =
        (unsigned long long*)(attw + (size_t)NPTS);     // NPTS u64
    float* part = (float*)(keys + (size_t)NPTS);        // 2*16384*32  = 1,048,576 f

    // 1. S-path GEMM -> loc, attw, keys-init  (67M MAC)
    gemm_s_fused<<<NROW / 64, 256, 0, stream>>>(query, Ws, bs, Wa, ba, qpts,
                                                loc, attw, keys);
    // 2. fused KNN argmin (atomicMin packed keys; exact first-min ties)
    knn_partial_kernel<<<dim3(NPTS / (KNN_THREADS * KNN_PPT), SLICES),
                         KNN_THREADS, 0, stream>>>(loc, ipts, keys);
    // 3. gather-blend + per-head value GEMM (134M MAC; 4x FLOP cut vs full
    //    value projection, via sum_p attw = 1 linearity)
    blend_gemm_kernel<<<dim3(NROW / 128, MH, 2), 256, 0, stream>>>(
        inp, attw, keys, Wv, part);
    // 4. output GEMM, merging K-halves + value bias (134M MAC)
    out_gemm_kernel<<<dim3(NROW / 64, CH / 32), 256, 0, stream>>>(
        part, bv, Wo, bo, out);
}

// Round 5
// 158.734 us; speedup vs baseline: 1.6992x; 1.0125x over previous
//
#include <hip/hip_runtime.h>

#define B_   2
#define LQ   1024
#define LIN  4096
#define CH   256
#define MH   8
#define NP   4
#define NROW (B_ * LQ)                  // 2048 (b,q) rows
#define NPTS (NROW * MH * NP)           // 65536 sampling points

#define SLICES    32
#define SLICE_LEN (LIN / SLICES)        // 128 candidates per slice
#define KNN_PPT   4
#define KNN_THREADS 256

// LDS row-swizzle: element (r,k) stored at [r][k ^ SWZ(r)]; SWZ is 4-aligned
// so b128 k-chunks stay contiguous and column-frag reads across 8 row-groups
// land in distinct banks (<=2-way).
#define SWZ(r) ((((r) >> 2) & 7) << 2)

// ---------------------------------------------------------------------------
// Fused S-path: S = query @ [Ws;Wa]^T + [bs;ba] (2048 x 128), then directly
//   loc[b,q,m,p,:] = query_points + S[row][m*12+p*3+e]
//   attw[b,q,m,p]  = softmax_p(S[row][96+m*4+p])
//   keys[b,q,m,p]  = u64 max (argmin identity for the knn atomicMin pass)
// 32 rows x 128 cols per block -> 64 blocks (was 32: only 12.5% of CUs).
// 256 threads, 2x8 micro-tile, BK=16.
// ---------------------------------------------------------------------------
__global__ __launch_bounds__(256)
void gemm_s_fused(const float* __restrict__ query,
                  const float* __restrict__ Ws, const float* __restrict__ bs,
                  const float* __restrict__ Wa, const float* __restrict__ ba,
                  const float* __restrict__ qpts,
                  float* __restrict__ loc, float* __restrict__ attw,
                  unsigned long long* __restrict__ keys) {
    __shared__ float As[16][32];
    __shared__ float Bs[16][128];
    __shared__ float Ss[32][132];
    const int tid = threadIdx.x;
    const int rowbase = blockIdx.x * 32;
    const int tx = tid & 15;          // col group (8 cols)
    const int ty = tid >> 4;          // row group (2 rows)

    const int lr  = tid >> 3;         // A-staging row 0..31
    const int lka = (tid & 7) * 2;    // A-staging k (float2)
    const float* Ap = query + (size_t)(rowbase + lr) * CH + lka;
    const int n   = tid >> 1;         // B-staging weight row
    const int lkb = (tid & 1) * 8;
    const float* Wrow = ((n < 96) ? (Ws + (size_t)n * CH)
                                  : (Wa + (size_t)(n - 96) * CH)) + lkb;
    float bj[8];
#pragma unroll
    for (int j = 0; j < 8; ++j) {
        int col = tx * 8 + j;
        bj[j] = (col < 96) ? bs[col] : ba[col - 96];
    }

    float2 a0 = *reinterpret_cast<const float2*>(Ap);
    float4 b0 = *reinterpret_cast<const float4*>(Wrow);
    float4 b1 = *reinterpret_cast<const float4*>(Wrow + 4);

    float acc[2][8] = {};
    for (int k0 = 0; k0 < CH; k0 += 16) {
        __syncthreads();
        As[lka + 0][lr] = a0.x; As[lka + 1][lr] = a0.y;
        Bs[lkb + 0][n] = b0.x; Bs[lkb + 1][n] = b0.y;
        Bs[lkb + 2][n] = b0.z; Bs[lkb + 3][n] = b0.w;
        Bs[lkb + 4][n] = b1.x; Bs[lkb + 5][n] = b1.y;
        Bs[lkb + 6][n] = b1.z; Bs[lkb + 7][n] = b1.w;
        __syncthreads();
        if (k0 + 16 < CH) {
            a0 = *reinterpret_cast<const float2*>(Ap + k0 + 16);
            b0 = *reinterpret_cast<const float4*>(Wrow + k0 + 16);
            b1 = *reinterpret_cast<const float4*>(Wrow + k0 + 20);
        }
#pragma unroll
        for (int k = 0; k < 16; ++k) {
            float2 a  = *reinterpret_cast<const float2*>(&As[k][ty << 1]);
            float4 v0 = *reinterpret_cast<const float4*>(&Bs[k][tx * 8]);
            float4 v1 = *reinterpret_cast<const float4*>(&Bs[k][tx * 8 + 4]);
            float ar[2] = {a.x, a.y};
            float br[8] = {v0.x, v0.y, v0.z, v0.w, v1.x, v1.y, v1.z, v1.w};
#pragma unroll
            for (int i = 0; i < 2; ++i)
#pragma unroll
                for (int j = 0; j < 8; ++j)
                    acc[i][j] = fmaf(ar[i], br[j], acc[i][j]);
        }
    }

    __syncthreads();
#pragma unroll
    for (int i = 0; i < 2; ++i)
#pragma unroll
        for (int j = 0; j < 8; ++j)
            Ss[ty * 2 + i][tx * 8 + j] = acc[i][j] + bj[j];
    __syncthreads();

    {   // epilogue: 256 units = 32 rows x 8 heads
        int row = tid >> 3;
        int m   = tid & 7;
        int r   = rowbase + row;
        const float* Sr = Ss[row];
        float q0 = qpts[r * 3 + 0], q1 = qpts[r * 3 + 1], q2 = qpts[r * 3 + 2];
#pragma unroll
        for (int p = 0; p < NP; ++p) {
            size_t o = ((size_t)(r * MH + m) * NP + p) * 3;
            loc[o + 0] = q0 + Sr[m * 12 + p * 3 + 0];
            loc[o + 1] = q1 + Sr[m * 12 + p * 3 + 1];
            loc[o + 2] = q2 + Sr[m * 12 + p * 3 + 2];
        }
        float l0 = Sr[96 + m * 4 + 0], l1 = Sr[96 + m * 4 + 1];
        float l2 = Sr[96 + m * 4 + 2], l3 = Sr[96 + m * 4 + 3];
        float mx = fmaxf(fmaxf(l0, l1), fmaxf(l2, l3));
        float e0 = expf(l0 - mx), e1 = expf(l1 - mx);
        float e2 = expf(l2 - mx), e3 = expf(l3 - mx);
        float inv = 1.0f / (e0 + e1 + e2 + e3);
        size_t ao = (size_t)(r * MH + m) * NP;
        attw[ao + 0] = e0 * inv; attw[ao + 1] = e1 * inv;
        attw[ao + 2] = e2 * inv; attw[ao + 3] = e3 * inv;
        unsigned long long* kp = keys + ao;
        kp[0] = kp[1] = kp[2] = kp[3] = 0xFFFFFFFFFFFFFFFFull;
    }
}

// ---------------------------------------------------------------------------
// KNN argmin via packed-key atomicMin. Grid (64, 32) = 2048 blocks -> 8
// blocks/CU = 32 waves/CU (round-4 version was 27% occupancy; latency from
// the cmp->select chains wasn't hidden). Min-update is the 3-op form
// {v_cmp, v_cndmask(idx from a VGPR counter), v_min} -- no per-update mov.
// Two trackers/pt (even/odd cands) keep 8 independent dep chains.
// ---------------------------------------------------------------------------
__global__ __launch_bounds__(KNN_THREADS)
void knn_partial_kernel(const float* __restrict__ loc, const float* __restrict__ ipts,
                        unsigned long long* __restrict__ keys) {
    __shared__ float4 pts[SLICE_LEN];
    const int slice = blockIdx.y;
    const int t0    = slice * SLICE_LEN;
    const int pt0   = blockIdx.x * (KNN_THREADS * KNN_PPT);
    const int b     = pt0 >> 15;                 // 32768 points per batch

    if (threadIdx.x < SLICE_LEN) {
        const float* sp = ipts + ((size_t)b * LIN + t0 + threadIdx.x) * 3;
        float x = sp[0], y = sp[1], z = sp[2];
        pts[threadIdx.x] = make_float4(x, y, z, fmaf(z, z, fmaf(y, y, x * x)));
    }

    float cx[KNN_PPT], cy[KNN_PPT], cz[KNN_PPT];
#pragma unroll
    for (int i = 0; i < KNN_PPT; ++i) {
        int p = pt0 + threadIdx.x + i * KNN_THREADS;
        cx[i] = -2.f * loc[(size_t)p * 3 + 0];
        cy[i] = -2.f * loc[(size_t)p * 3 + 1];
        cz[i] = -2.f * loc[(size_t)p * 3 + 2];
    }

    float bd0[KNN_PPT], bd1[KNN_PPT];
    int   bi0[KNN_PPT], bi1[KNN_PPT];
#pragma unroll
    for (int i = 0; i < KNN_PPT; ++i) {
        bd0[i] = bd1[i] = 1e30f;
        bi0[i] = bi1[i] = t0;
    }

    __syncthreads();
    int ca = t0;                        // candidate-index VGPR counter
#pragma unroll 2
    for (int l = 0; l < SLICE_LEN; l += 4) {
        float4 p0 = pts[l + 0];
        float4 p1 = pts[l + 1];
        float4 p2 = pts[l + 2];
        float4 p3 = pts[l + 3];
        int c1 = ca + 1, c2 = ca + 2, c3 = ca + 3;
#pragma unroll
        for (int i = 0; i < KNN_PPT; ++i) {
            float d0 = fmaf(cx[i], p0.x, fmaf(cy[i], p0.y, fmaf(cz[i], p0.z, p0.w)));
            float d1 = fmaf(cx[i], p1.x, fmaf(cy[i], p1.y, fmaf(cz[i], p1.z, p1.w)));
            float d2 = fmaf(cx[i], p2.x, fmaf(cy[i], p2.y, fmaf(cz[i], p2.z, p2.w)));
            float d3 = fmaf(cx[i], p3.x, fmaf(cy[i], p3.y, fmaf(cz[i], p3.z, p3.w)));
            // tracker 0: even candidates (scan order l, l+2)
            bool a0 = d0 < bd0[i];
            bi0[i] = a0 ? ca : bi0[i];
            bd0[i] = fminf(bd0[i], d0);
            bool a2 = d2 < bd0[i];
            bi0[i] = a2 ? c2 : bi0[i];
            bd0[i] = fminf(bd0[i], d2);
            // tracker 1: odd candidates (l+1, l+3)
            bool a1 = d1 < bd1[i];
            bi1[i] = a1 ? c1 : bi1[i];
            bd1[i] = fminf(bd1[i], d1);
            bool a3 = d3 < bd1[i];
            bi1[i] = a3 ? c3 : bi1[i];
            bd1[i] = fminf(bd1[i], d3);
        }
        ca += 4;
    }

#pragma unroll
    for (int i = 0; i < KNN_PPT; ++i) {
        // lexicographic (d, idx) merge of the two trackers = first-min
        float d = bd0[i]; int ix = bi0[i];
        if (bd1[i] < d || (bd1[i] == d && bi1[i] < ix)) { d = bd1[i]; ix = bi1[i]; }
        unsigned int ub  = __float_as_uint(d);
        unsigned int k32 = ub ^ (((unsigned int)((int)ub >> 31)) | 0x80000000u);
        unsigned long long key = ((unsigned long long)k32 << 32) | (unsigned int)ix;
        int p = pt0 + threadIdx.x + i * KNN_THREADS;
        atomicMin(&keys[p], key);
    }
}

// ---------------------------------------------------------------------------
// blend_gemm: out1_m = (sum_p attw_p * inp[idx_p]) @ Wv_m^T   (per head m)
// sum_p attw = 1 linearity: 16.8M-MAC blend + 134M-MAC thin GEMM replaces
// the 537M-MAC value GEMM + gather. part[ks][((m*NROW+bq)*32+d)]
// ---------------------------------------------------------------------------
__global__ __launch_bounds__(256)
void blend_gemm_kernel(const float* __restrict__ inp, const float* __restrict__ attw,
                       const unsigned long long* __restrict__ keys,
                       const float* __restrict__ Wv, float* __restrict__ part) {
    __shared__ float Ab[128][132];   // blended rows, k-major, swizzled
    __shared__ float Bs[32][132];    // Wv_m half, k-major, swizzled
    __shared__ int   ids[128][4];
    __shared__ float ats[128][4];
    const int t  = threadIdx.x;
    const int rb = blockIdx.x * 128;     // bq base
    const int m  = blockIdx.y;
    const int ks = blockIdx.z;
    const int k0 = ks * 128;

    if (t < 128) {
        size_t base = ((size_t)(rb + t) * MH + m) * NP;
#pragma unroll
        for (int p = 0; p < NP; ++p) {
            ids[t][p] = (int)(keys[base + p] & 0xFFFFFFFFull);
            ats[t][p] = attw[base + p];
        }
    }
#pragma unroll
    for (int pass = 0; pass < 4; ++pass) {
        int u  = pass * 256 + t;
        int nn = u >> 5;                 // 0..31
        int cg = (u & 31) * 4;           // 0..124
        float4 w = *reinterpret_cast<const float4*>(Wv + (size_t)(m * 32 + nn) * CH + k0 + cg);
        *reinterpret_cast<float4*>(&Bs[nn][cg ^ SWZ(nn)]) = w;
    }
    __syncthreads();

#pragma unroll
    for (int pass = 0; pass < 16; ++pass) {
        int u   = pass * 256 + t;
        int row = u >> 5;                // 0..127
        int cg  = (u & 31) * 4;          // coalesced 512B per row-group
        int bq  = rb + row;
        const float* ib = inp + ((size_t)(bq >> 10) * LIN) * CH + k0 + cg;
        float4 a = {0.f, 0.f, 0.f, 0.f};
#pragma unroll
        for (int p = 0; p < NP; ++p) {
            float4 v = *reinterpret_cast<const float4*>(ib + (size_t)ids[row][p] * CH);
            float w = ats[row][p];
            a.x = fmaf(w, v.x, a.x); a.y = fmaf(w, v.y, a.y);
            a.z = fmaf(w, v.z, a.z); a.w = fmaf(w, v.w, a.w);
        }
        *reinterpret_cast<float4*>(&Ab[row][cg ^ SWZ(row)]) = a;
    }
    __syncthreads();

    const int ty = t >> 3;               // 0..31 -> rows ty*4..
    const int tx = t & 7;                // 0..7  -> cols tx*4..
    const int sA = SWZ(ty * 4);
    const int sB = SWZ(tx * 4);
    float acc[4][4] = {};
    for (int k = 0; k < 128; k += 4) {
        float4 a[4], b[4];
#pragma unroll
        for (int i = 0; i < 4; ++i)
            a[i] = *reinterpret_cast<const float4*>(&Ab[ty * 4 + i][k ^ sA]);
#pragma unroll
        for (int j = 0; j < 4; ++j)
            b[j] = *reinterpret_cast<const float4*>(&Bs[tx * 4 + j][k ^ sB]);
#pragma unroll
        for (int i = 0; i < 4; ++i)
#pragma unroll
            for (int j = 0; j < 4; ++j)
                acc[i][j] = fmaf(a[i].x, b[j].x, fmaf(a[i].y, b[j].y,
                             fmaf(a[i].z, b[j].z, fmaf(a[i].w, b[j].w, acc[i][j]))));
    }
#pragma unroll
    for (int i = 0; i < 4; ++i) {
        int bq = rb + ty * 4 + i;
        float4 c = {acc[i][0], acc[i][1], acc[i][2], acc[i][3]};
        *reinterpret_cast<float4*>(part + ((size_t)ks * MH * NROW + (size_t)m * NROW + bq) * 32 + tx * 4) = c;
    }
}

// ---------------------------------------------------------------------------
// out_gemm: out = (part0 + part1 + bv) @ Wo^T + bo   (2048 x 256, K=256)
// 64x32 tiles -> grid (32,8) = 256 blocks.
// ---------------------------------------------------------------------------
__global__ __launch_bounds__(256)
void out_gemm_kernel(const float* __restrict__ part, const float* __restrict__ bv,
                     const float* __restrict__ Wo, const float* __restrict__ bo,
                     float* __restrict__ out) {
    __shared__ float Ab[64][260];
    __shared__ float Bs[32][260];
    const int t  = threadIdx.x;
    const int rb = blockIdx.x * 64;
    const int nb = blockIdx.y * 32;

#pragma unroll
    for (int pass = 0; pass < 16; ++pass) {
        int u   = pass * 256 + t;
        int row = u >> 6;                // 0..63
        int cg  = (u & 63) * 4;          // 0..252
        int bq  = rb + row;
        int mm  = cg >> 5, d = cg & 31;
        size_t pi = ((size_t)mm * NROW + bq) * 32 + d;
        float4 v0 = *reinterpret_cast<const float4*>(part + pi);
        float4 v1 = *reinterpret_cast<const float4*>(part + (size_t)MH * NROW * 32 + pi);
        float4 bb = *reinterpret_cast<const float4*>(bv + cg);
        float4 a  = {v0.x + v1.x + bb.x, v0.y + v1.y + bb.y,
                     v0.z + v1.z + bb.z, v0.w + v1.w + bb.w};
        *reinterpret_cast<float4*>(&Ab[row][cg ^ SWZ(row)]) = a;
    }
#pragma unroll
    for (int pass = 0; pass < 8; ++pass) {
        int u  = pass * 256 + t;
        int nn = u >> 6;                 // 0..31
        int cg = (u & 63) * 4;
        float4 w = *reinterpret_cast<const float4*>(Wo + (size_t)(nb + nn) * CH + cg);
        *reinterpret_cast<float4*>(&Bs[nn][cg ^ SWZ(nn)]) = w;
    }
    __syncthreads();

    const int ty = t >> 3;               // 0..31 -> rows ty*2..
    const int tx = t & 7;                // 0..7  -> cols tx*4..
    const int sA = SWZ(ty * 2);
    const int sB = SWZ(tx * 4);
    float acc[2][4] = {};
    for (int k = 0; k < 256; k += 4) {
        float4 a[2], b[4];
#pragma unroll
        for (int i = 0; i < 2; ++i)
            a[i] = *reinterpret_cast<const float4*>(&Ab[ty * 2 + i][k ^ sA]);
#pragma unroll
        for (int j = 0; j < 4; ++j)
            b[j] = *reinterpret_cast<const float4*>(&Bs[tx * 4 + j][k ^ sB]);
#pragma unroll
        for (int i = 0; i < 2; ++i)
#pragma unroll
            for (int j = 0; j < 4; ++j)
                acc[i][j] = fmaf(a[i].x, b[j].x, fmaf(a[i].y, b[j].y,
                             fmaf(a[i].z, b[j].z, fmaf(a[i].w, b[j].w, acc[i][j]))));
    }
#pragma unroll
    for (int i = 0; i < 2; ++i) {
        int bq = rb + ty * 2 + i;
        int n  = nb + tx * 4;
        float4 c = {acc[i][0] + bo[n + 0], acc[i][1] + bo[n + 1],
                    acc[i][2] + bo[n + 2], acc[i][3] + bo[n + 3]};
        *reinterpret_cast<float4*>(out + (size_t)bq * CH + n) = c;
    }
}

// ---------------------------------------------------------------------------
extern "C" void kernel_launch(void* const* d_in, const int* in_sizes, int n_in,
                              void* d_out, int out_size, void* d_ws, size_t ws_size,
                              hipStream_t stream) {
    const float* query = (const float*)d_in[0];
    const float* qpts  = (const float*)d_in[1];
    const float* inp   = (const float*)d_in[2];
    const float* ipts  = (const float*)d_in[3];
    const float* Wv    = (const float*)d_in[4];
    const float* bv    = (const float*)d_in[5];
    const float* Ws    = (const float*)d_in[6];
    const float* bs    = (const float*)d_in[7];
    const float* Wa    = (const float*)d_in[8];
    const float* ba    = (const float*)d_in[9];
    const float* Wo    = (const float*)d_in[10];
    const float* bo    = (const float*)d_in[11];
    float* out = (float*)d_out;

    float* ws   = (float*)d_ws;
    float* loc  = ws;                                   // NPTS*3 f
    float* attw = loc + (size_t)NPTS * 3;               // NPTS f
    unsigned long long* keys =
        (unsigned long long*)(attw + (size_t)NPTS);     // NPTS u64
    float* part = (float*)(keys + (size_t)NPTS);        // 2*MH*NROW*32 f

    // 1. S-path GEMM -> loc, attw, keys-init (67M MAC, 64 blocks)
    gemm_s_fused<<<NROW / 32, 256, 0, stream>>>(query, Ws, bs, Wa, ba, qpts,
                                                loc, attw, keys);
    // 2. fused KNN argmin (atomicMin packed keys; exact first-min ties)
    knn_partial_kernel<<<dim3(NPTS / (KNN_THREADS * KNN_PPT), SLICES),
                         KNN_THREADS, 0, stream>>>(loc, ipts, keys);
    // 3. gather-blend + per-head value GEMM (134M MAC)
    blend_gemm_kernel<<<dim3(NROW / 128, MH, 2), 256, 0, stream>>>(
        inp, attw, keys, Wv, part);
    // 4. output GEMM, merging K-halves + value bias (134M MAC)
    out_gemm_kernel<<<dim3(NROW / 64, CH / 32), 256, 0, stream>>>(
        part, bv, Wo, bo, out);
}